// Round 8
// baseline (2889.790 us; speedup 1.0000x reference)
//
#include <hip/hip_runtime.h>
#include <stdint.h>

// CharRNN MI355X — persistent-RNN, pipelined-poll + early-publish edition.
//   Geometry (r7): 256 blocks, 16 groups x 16 blocks. Block (gi,gj):
//   rows gi*16..+16, cols gj*64..+64. W_hh slice bf16 frag-order in LDS.
//   Per step: wave w coherent-loads A-frags for K in [w*256,(w+1)*256),
//   MFMAs partials for 4 n-tiles, LDS cross-wave reduce, tanh, coherent
//   store, per-WAVE drain (s_waitcnt vmcnt0) + per-wave flag publish
//   BEFORE the end barrier; consumers poll 16 wave-flags with 4
//   outstanding pipelined loads (poll period ~RT/4).
//   Every 16 steps: inline logits for tsel=t-15+gj -> d_out.
// d_ws: proj f32 @0 (256KB) | whof @256K (128KB) | flags @384K (128KB) |
//       ring bf16 @1MB (16MB).

#define BATCH 256
#define SEQ   512
#define HID   1024
#define VOC   64
#define EMB   256
#define FINAL_OFF (BATCH * SEQ * VOC)   // 8388608
#define NSLOT 32

typedef __attribute__((ext_vector_type(8))) short short8;
typedef __attribute__((ext_vector_type(4))) float f32x4;
typedef unsigned long long u64;

__device__ inline unsigned short f2bf(float f) {
  union { float f; unsigned u; } v; v.f = f;
  unsigned u = v.u;
  return (unsigned short)((u + 0x7FFFu + ((u >> 16) & 1u)) >> 16);  // RNE
}
__device__ inline float bf2f(unsigned short b) {
  union { unsigned u; float f; } v; v.u = ((unsigned)b) << 16; return v.f;
}
__device__ inline u64 cload64(const void* p) {
  return __hip_atomic_load((const u64*)p, __ATOMIC_RELAXED,
                           __HIP_MEMORY_SCOPE_AGENT);
}
__device__ inline unsigned cload32(const void* p) {
  return __hip_atomic_load((const unsigned*)p, __ATOMIC_RELAXED,
                           __HIP_MEMORY_SCOPE_AGENT);
}
__device__ inline void cstore32(void* p, unsigned v) {
  __hip_atomic_store((unsigned*)p, v, __ATOMIC_RELAXED,
                     __HIP_MEMORY_SCOPE_AGENT);
}
__device__ inline short8 comb(u64 lo, u64 hi) {
  union { u64 d[2]; short8 s; } c; c.d[0] = lo; c.d[1] = hi; return c.s;
}

// Pipelined poll: 4 outstanding loads of this lane's flag per round.
// Exits as soon as the earliest returning load shows the target.
__device__ inline void poll4(const unsigned* fp, unsigned target) {
  int guard = 0;
  for (;;) {
    unsigned f0 = cload32(fp);
    unsigned f1 = cload32(fp);
    unsigned f2 = cload32(fp);
    unsigned f3 = cload32(fp);
    if (__ballot(f0 >= target) == ~0ull) break;
    if (__ballot(f1 >= target) == ~0ull) break;
    if (__ballot(f2 >= target) == ~0ull) break;
    if (__ballot(f3 >= target) == ~0ull) break;
    __builtin_amdgcn_s_sleep(1);
    if (++guard > (1 << 13)) break;      // bailout: wrong answer beats a hang
  }
}

// ---------------- K1: projection table -------------------------------------
__global__ __launch_bounds__(256) void k_prep(const float* __restrict__ emb,
                                              const float* __restrict__ Wih,
                                              const float* __restrict__ bh,
                                              float* __restrict__ proj) {
  __shared__ float es[EMB];
  const int v = blockIdx.x >> 2;
  const int p = blockIdx.x & 3;
  const int tid = threadIdx.x;
  es[tid] = emb[v * EMB + tid];
  __syncthreads();
  const int h = p * 256 + tid;
  float acc = bh[h];
  for (int e = 0; e < EMB; ++e) acc += es[e] * Wih[e * HID + h];
  proj[v * HID + h] = acc;
}

// ---------------- K1b: W_ho -> fragment order ------------------------------
__global__ __launch_bounds__(256) void k_prep2(const float* __restrict__ Who,
                                               unsigned short* __restrict__ whof) {
  int u = blockIdx.x * 256 + threadIdx.x;          // 65536 total
  int j = u & 7, v = (u >> 3) & 63, q = (u >> 9) & 3, kb = u >> 11;
  whof[u] = f2bf(Who[(kb * 32 + q * 8 + j) * VOC + v]);
}

// ---------------- K2: persistent recurrence + inline logits ----------------
// LDS: w_lds 131072 | red 16384 | p_lds 8192  => 155648
__global__ __launch_bounds__(256, 1) void k_rnn(
    const int* __restrict__ x, const float* __restrict__ Whh,
    const float* __restrict__ proj, const unsigned short* __restrict__ whof,
    const float* __restrict__ bo, unsigned short* __restrict__ ring,
    unsigned* __restrict__ flags, float* __restrict__ out,
    float* __restrict__ final_out) {
  extern __shared__ char smem[];
  unsigned short* w_lds = (unsigned short*)smem;             // 131072
  float*          red   = (float*)(smem + 131072);           // 16384
  unsigned short* p_lds = (unsigned short*)(smem + 147456);  // 8192

  const int tid = threadIdx.x, bid = blockIdx.x;
  const int gi = ((bid & 7) << 1) | ((bid >> 3) & 1);        // 0..15 (XCD swz)
  const int gj = bid >> 4;                                   // 0..15
  const int row0 = gi * 16, colb = gj * 64;
  const int w = tid >> 6, lane = tid & 63;
  const int l15 = lane & 15, q = lane >> 4;

  // W_hh column slice -> LDS bf16 frag order [kb][q][n][j]  (once)
  for (int it = 0; it < 256; ++it) {
    int u = it * 256 + tid;
    int j = u & 7, n = (u >> 3) & 63, qq = (u >> 9) & 3, kb = u >> 11;
    w_lds[u] = f2bf(Whh[(kb * 32 + qq * 8 + j) * HID + colb + n]);
  }
  // proj slice [64 voc][64 local cols] -> LDS bf16          (once)
  for (int it = 0; it < 16; ++it) {
    int u = it * 256 + tid;
    p_lds[u] = f2bf(proj[(u >> 6) * HID + colb + (u & 63)]);
  }
  __syncthreads();

  const float biasv = bo[w * 16 + l15];
  // my wave's flag line; consumers' flag lines for my K-range producers
  unsigned* myflag = flags + (size_t)(((gi * 16 + gj) * 4) + w) * 32;
  const unsigned* cons_fb =
      flags + (size_t)((gi * 16 + w * 4 + ((lane >> 2) & 3)) * 4 + (lane & 3)) * 32;
  const unsigned* log_fb =
      flags + (size_t)((gi * 16 + (lane >> 2)) * 4 + (lane & 3)) * 32;

  for (int t = 0; t < SEQ; ++t) {
    // 0) x values for this lane's 4 rows (cached loads, overlap the poll)
    int xrow[4];
    #pragma unroll
    for (int r = 0; r < 4; ++r) xrow[r] = x[(row0 + q * 4 + r) * SEQ + t];

    f32x4 a0 = {0.f,0.f,0.f,0.f}, a1 = {0.f,0.f,0.f,0.f};
    f32x4 a2 = {0.f,0.f,0.f,0.f}, a3 = {0.f,0.f,0.f,0.f};
    if (t > 0) {
      // 1) pipelined-poll the 16 wave-flags of my K-range, then stream A
      poll4(cons_fb + ((t - 1) & (NSLOT - 1)), (unsigned)t);
      const unsigned short* sp =
          ring + (size_t)((t - 1) & (NSLOT - 1)) * (BATCH * HID) +
          (size_t)(row0 + l15) * HID + w * 256 + q * 8;
      u64 alo[8], ahi[8];
      #pragma unroll
      for (int kk = 0; kk < 8; ++kk) {
        alo[kk] = cload64(sp + kk * 32);
        ahi[kk] = cload64(sp + kk * 32 + 4);
      }
      #pragma unroll
      for (int kk = 0; kk < 8; ++kk) {
        short8 af = comb(alo[kk], ahi[kk]);
        int kb = w * 8 + kk;
        const unsigned short* bb = w_lds + (size_t)((kb * 4 + q) * 64) * 8;
        a0 = __builtin_amdgcn_mfma_f32_16x16x32_bf16(af, *(const short8*)(bb + l15 * 8),        a0, 0, 0, 0);
        a1 = __builtin_amdgcn_mfma_f32_16x16x32_bf16(af, *(const short8*)(bb + (16 + l15) * 8), a1, 0, 0, 0);
        a2 = __builtin_amdgcn_mfma_f32_16x16x32_bf16(af, *(const short8*)(bb + (32 + l15) * 8), a2, 0, 0, 0);
        a3 = __builtin_amdgcn_mfma_f32_16x16x32_bf16(af, *(const short8*)(bb + (48 + l15) * 8), a3, 0, 0, 0);
      }
      if (w != 0) *(f32x4*)(red + ((w * 4 + 0) * 64 + lane) * 4) = a0;
      if (w != 1) *(f32x4*)(red + ((w * 4 + 1) * 64 + lane) * 4) = a1;
      if (w != 2) *(f32x4*)(red + ((w * 4 + 2) * 64 + lane) * 4) = a2;
      if (w != 3) *(f32x4*)(red + ((w * 4 + 3) * 64 + lane) * 4) = a3;
    }
    __syncthreads();                       // sync1: reduce visibility
    f32x4 own = (w == 0) ? a0 : (w == 1) ? a1 : (w == 2) ? a2 : a3;
    if (t > 0) {
      #pragma unroll
      for (int w2 = 0; w2 < 4; ++w2) {
        if (w2 != w) {
          f32x4 p = *(const f32x4*)(red + ((w2 * 4 + w) * 64 + lane) * 4);
          own[0] += p[0]; own[1] += p[1]; own[2] += p[2]; own[3] += p[3];
        }
      }
    }
    // 2) epilogue: wave w owns n-tile w (cols w*16..+16)
    unsigned short* st = ring + (size_t)(t & (NSLOT - 1)) * (BATCH * HID);
    const int colg = colb + w * 16 + l15;
    float hv[4];
    #pragma unroll
    for (int r = 0; r < 4; ++r) {
      float pre = bf2f(p_lds[xrow[r] * 64 + w * 16 + l15]) + own[r];
      hv[r] = tanhf(pre);
      if (t == SEQ - 1) final_out[(row0 + q * 4 + r) * HID + colg] = hv[r];
    }
    #pragma unroll
    for (int r = 0; r < 4; ++r) {
      unsigned m = f2bf(hv[r]);
      unsigned o = (unsigned)__shfl_xor((int)m, 1);
      if (!(l15 & 1))
        cstore32(st + (size_t)(row0 + q * 4 + r) * HID + colg, m | (o << 16));
    }
    // 3) per-WAVE drain + early flag publish (before the end barrier)
    __builtin_amdgcn_s_waitcnt(0xF70);     // vmcnt(0) only
    if (lane == 0) cstore32(myflag + (t & (NSLOT - 1)), (unsigned)(t + 1));
    __syncthreads();                       // sync2: protect red for next iter
    // 4) logits every 16 steps: group rows x tsel=t-15+gj x all 64 voc
    if ((t & 15) == 15) {
      int tsel = t - 15 + gj;              // <= t
      poll4(log_fb + (tsel & (NSLOT - 1)), (unsigned)(tsel + 1));
      const unsigned short* ap =
          ring + (size_t)(tsel & (NSLOT - 1)) * (BATCH * HID) +
          (size_t)(row0 + l15) * HID + q * 8;
      f32x4 lc = {0.f,0.f,0.f,0.f};
      for (int c = 0; c < 4; ++c) {
        u64 alo[8], ahi[8];
        #pragma unroll
        for (int kk = 0; kk < 8; ++kk) {
          alo[kk] = cload64(ap + (c * 8 + kk) * 32);
          ahi[kk] = cload64(ap + (c * 8 + kk) * 32 + 4);
        }
        #pragma unroll
        for (int kk = 0; kk < 8; ++kk) {
          int kb = c * 8 + kk;
          short8 bf = *(const short8*)(whof + (size_t)((kb * 4 + q) * 64 + w * 16 + l15) * 8);
          lc = __builtin_amdgcn_mfma_f32_16x16x32_bf16(comb(alo[kk], ahi[kk]), bf, lc, 0, 0, 0);
        }
      }
      #pragma unroll
      for (int r = 0; r < 4; ++r)
        out[((size_t)(row0 + q * 4 + r) * SEQ + tsel) * VOC + w * 16 + l15] =
            lc[r] + biasv;
    }
  }
}

// ---------------- launch ----------------------------------------------------
extern "C" void kernel_launch(void* const* d_in, const int* in_sizes, int n_in,
                              void* d_out, int out_size, void* d_ws, size_t ws_size,
                              hipStream_t stream) {
  const int*   x   = (const int*)d_in[0];
  const float* emb = (const float*)d_in[1];
  const float* Wih = (const float*)d_in[2];
  const float* Whh = (const float*)d_in[3];
  const float* bh  = (const float*)d_in[4];
  const float* Who = (const float*)d_in[5];
  const float* bo  = (const float*)d_in[6];
  float* out = (float*)d_out;

  char* ws = (char*)d_ws;
  float*          proj  = (float*)ws;                         // 262144 B
  unsigned short* whof  = (unsigned short*)(ws + 262144);     // 131072 B
  unsigned*       flags = (unsigned*)(ws + 393216);           // 131072 B
  unsigned short* ring  = (unsigned short*)(ws + (1 << 20));  // 16 MiB

  size_t need = (size_t)(1 << 20) + (size_t)NSLOT * BATCH * HID * 2;
  if (ws_size < need) return;  // diagnostic fail instead of a fault

  (void)hipFuncSetAttribute(reinterpret_cast<const void*>(k_rnn),
                            hipFuncAttributeMaxDynamicSharedMemorySize, 155648);

  k_prep<<<256, 256, 0, stream>>>(emb, Wih, bh, proj);
  k_prep2<<<256, 256, 0, stream>>>(Who, whof);
  hipMemsetAsync(flags, 0, 131072, stream);
  k_rnn<<<256, 256, 155648, stream>>>(x, Whh, proj, whof, bo, ring, flags,
                                      out, out + FINAL_OFF);
}